// Round 15
// baseline (107.663 us; speedup 1.0000x reference)
//
#include <hip/hip_runtime.h>
#include <stdint.h>

#define DEMB 1024
#define NHEAD 16
#define DHEAD 64
#define SEQ 2048
#define MROWS 4096  // B*S

typedef __bf16 bf16x8 __attribute__((ext_vector_type(8)));
typedef float f32x4 __attribute__((ext_vector_type(4)));
typedef unsigned short u16;

#define LOG2E 1.44269504088896340736f

__device__ __forceinline__ u16 f2b(float f) {
  return __builtin_bit_cast(u16, (__bf16)f);  // RNE, compiler can pack pairs
}
__device__ __forceinline__ uint32_t pk2(float a, float b) {
  return (uint32_t)f2b(a) | ((uint32_t)f2b(b) << 16);
}

__device__ __forceinline__ f32x4 mfma16(bf16x8 a, bf16x8 b, f32x4 c) {
  return __builtin_amdgcn_mfma_f32_16x16x32_bf16(a, b, c, 0, 0, 0);
}

__device__ __forceinline__ void gload_lds16(const void* g, void* l) {
  __builtin_amdgcn_global_load_lds(
      (__attribute__((address_space(1))) unsigned int*)(g),
      (__attribute__((address_space(3))) unsigned int*)(l), 16, 0, 0);
}

// fused fp32->bf16 convert of three regions (sizes all multiples of 4)
__global__ void cvt3_f32_bf16(const float* __restrict__ a, int na,
                              const float* __restrict__ b, int nb,
                              const float* __restrict__ c, int nc,
                              u16* __restrict__ da, u16* __restrict__ db,
                              u16* __restrict__ dc) {
  const int total = (na + nb + nc) >> 2;
  const int stride = gridDim.x * blockDim.x;
  for (int t = blockIdx.x * blockDim.x + threadIdx.x; t < total; t += stride) {
    int i = t << 2;
    const float* s;
    u16* d;
    if (i < na) {
      s = a + i; d = da + i;
    } else if (i < na + nb) {
      s = b + (i - na); d = db + (i - na);
    } else {
      s = c + (i - na - nb); d = dc + (i - na - nb);
    }
    float4 f = *(const float4*)s;
    ushort4 o;
    o.x = f2b(f.x); o.y = f2b(f.y); o.z = f2b(f.z); o.w = f2b(f.w);
    *(ushort4*)d = o;
  }
}

// NT GEMM (round-8 proven body, occupancy-first).
// EPI==0: scatter Q,K to [B,H,S,Dh] bf16 (Q pre-scaled by 0.125*log2e);
//         V written TRANSPOSED: Vt[bh][d][s].
// EPI==1: write fp32 C[m*N+n].
template <int EPI>
__global__ __launch_bounds__(256, 4) void gemm_nt(
    const u16* __restrict__ A, const u16* __restrict__ Bw,
    const float* __restrict__ bias, int K, int N,
    u16* __restrict__ q_out, u16* __restrict__ k_out, u16* __restrict__ v_out,
    float* __restrict__ f_out) {
  __shared__ __align__(16) u16 As[128 * 64];
  __shared__ __align__(16) u16 Bs[128 * 64];
  const int tid = threadIdx.x;
  const int w = tid >> 6;
  const int lane = tid & 63;
  const int wm = w >> 1, wn = w & 1;
  const int m0 = blockIdx.y * 128, n0 = blockIdx.x * 128;
  const int l16 = lane & 15, lg = lane >> 4;
  const int st_row = lane >> 3, st_slot = lane & 7;

  f32x4 acc[4][4] = {};

  for (int k0 = 0; k0 < K; k0 += 64) {
#pragma unroll
    for (int i = 0; i < 4; ++i) {
      const int chunk = (w << 2) | i;
      const int row = (chunk << 3) | st_row;
      const int scol = (st_slot ^ (row & 7)) << 3;
      gload_lds16(A + (size_t)(m0 + row) * K + k0 + scol, (char*)As + (chunk << 10));
      gload_lds16(Bw + (size_t)(n0 + row) * K + k0 + scol, (char*)Bs + (chunk << 10));
    }
    __syncthreads();
#pragma unroll
    for (int ks = 0; ks < 2; ++ks) {
      bf16x8 af[4], bfr[4];
#pragma unroll
      for (int mi = 0; mi < 4; ++mi) {
        const int row = wm * 64 + mi * 16 + l16;
        const int cb = ((ks << 6) | (lg << 4)) ^ ((row & 7) << 4);
        af[mi] = *(const bf16x8*)((const char*)As + row * 128 + cb);
      }
#pragma unroll
      for (int ni = 0; ni < 4; ++ni) {
        const int row = wn * 64 + ni * 16 + l16;
        const int cb = ((ks << 6) | (lg << 4)) ^ ((row & 7) << 4);
        bfr[ni] = *(const bf16x8*)((const char*)Bs + row * 128 + cb);
      }
#pragma unroll
      for (int mi = 0; mi < 4; ++mi)
#pragma unroll
        for (int ni = 0; ni < 4; ++ni)
          acc[mi][ni] = mfma16(af[mi], bfr[ni], acc[mi][ni]);
    }
    __syncthreads();
  }

#pragma unroll
  for (int ni = 0; ni < 4; ++ni) {
    const int n = n0 + wn * 64 + ni * 16 + l16;
    const float bv = bias[n];
    if (EPI == 0) {
      const int part = n >> 10;
      const int hh = (n >> 6) & 15;
      const int dh = n & 63;
      if (part == 2) {
        // V^T: [bh][d][s], 4 consecutive s per ushort4
#pragma unroll
        for (int mi = 0; mi < 4; ++mi) {
          const int mbase = m0 + wm * 64 + mi * 16 + (lg << 2);
          const int bq = mbase >> 11, s0 = mbase & 2047;
          ushort4 o;
          o.x = f2b(acc[mi][ni][0] + bv);
          o.y = f2b(acc[mi][ni][1] + bv);
          o.z = f2b(acc[mi][ni][2] + bv);
          o.w = f2b(acc[mi][ni][3] + bv);
          *(ushort4*)(v_out + ((size_t)(((bq << 4) | hh) * 64 + dh)) * SEQ + s0) = o;
        }
      } else {
        const float scl = (part == 0) ? (0.125f * LOG2E) : 1.0f;
        u16* dst = (part == 0) ? q_out : k_out;
#pragma unroll
        for (int mi = 0; mi < 4; ++mi) {
#pragma unroll
          for (int i = 0; i < 4; ++i) {
            const int m = m0 + wm * 64 + mi * 16 + (lg << 2) + i;
            const int bq = m >> 11, s = m & 2047;
            dst[((size_t)((bq << 4) | hh) * SEQ + s) * DHEAD + dh] = f2b((acc[mi][ni][i] + bv) * scl);
          }
        }
      }
    } else {
#pragma unroll
      for (int mi = 0; mi < 4; ++mi)
#pragma unroll
        for (int i = 0; i < 4; ++i) {
          const int m = m0 + wm * 64 + mi * 16 + (lg << 2) + i;
          f_out[(size_t)m * N + n] = acc[mi][ni][i] + bv;
        }
    }
  }
}

// ---- attention: 4 waves, QBLK=64, KVBLK=64, 4 blocks/CU (40 KB LDS) ----
__device__ __forceinline__ int swz4(int r) { return (r ^ (r >> 3)) & 15; }

// K tile 64kv x 64d packed: LDS [32 rows][256B]; row r2 holds kv {2r2, 2r2+1}.
// Unswizzled slot s (0..15): kv = 2*r2 + (s>>3), d = (s&7)*8..+7.
__device__ __forceinline__ void stage_k64(const u16* __restrict__ Kb, size_t base,
                                          int jt, u16* Ks, int w, int lane) {
#pragma unroll
  for (int i = 0; i < 2; ++i) {
    const int g = (w << 1) | i;               // 0..7: 1KB chunk
    const int row = (g << 2) | (lane >> 4);   // 0..31
    const int sh = (lane & 15) ^ swz4(row);
    const int kv = (row << 1) | (sh >> 3);
    const int del = (sh & 7) << 3;
    gload_lds16(Kb + base + (size_t)(jt * 64 + kv) * DHEAD + del,
                (char*)Ks + (g << 10));
  }
}

// V^T tile 64d x 64kv packed: LDS [32 rows][256B]; row r2 holds d {2r2, 2r2+1}.
// Unswizzled slot s: d = 2*r2 + (s>>3), kv = (s&7)*8..+7.
__device__ __forceinline__ void stage_v64(const u16* __restrict__ VTg, size_t base,
                                          int jt, u16* Vs, int w, int lane) {
#pragma unroll
  for (int i = 0; i < 2; ++i) {
    const int g = (w << 1) | i;
    const int row = (g << 2) | (lane >> 4);
    const int sh = (lane & 15) ^ swz4(row);
    const int d = (row << 1) | (sh >> 3);
    gload_lds16(VTg + base + (size_t)d * SEQ + jt * 64 + ((sh & 7) << 3),
                (char*)Vs + (g << 10));
  }
}

// Swapped-operand flash attention. One q-tile (qi) per block; 1024 blocks ->
// exactly 4 blocks/CU (40 KB LDS), doubling independent latency-hiding
// contexts vs the 512-block config. qi decode balances the 4 stride-256
// co-resident blocks per CU-slot to a constant 62 iterations.
__global__ __launch_bounds__(256, 4) void attn_fwd(
    const u16* __restrict__ Qb, const u16* __restrict__ Kb,
    const u16* __restrict__ VTg, u16* __restrict__ Ob,
    const int* __restrict__ amask) {
  __shared__ __align__(16) u16 Ks[2][32 * 128];   // 2 x 8 KB
  __shared__ __align__(16) u16 Vt[2][32 * 128];   // 2 x 8 KB
  __shared__ __align__(16) uint32_t Ps[4][512];   // 8 KB (2 KB/wave)
  const int tid = threadIdx.x;
  const int w = tid >> 6, lane = tid & 63;
  const int l16 = lane & 15, lg = lane >> 4;

  const int id = blockIdx.x;
  const int k5 = id >> 5;                 // 0..31
  const int jj = k5 & 7, qq = k5 >> 3;
  const int qi = (qq == 0) ? 31 - jj : (qq == 1) ? jj : (qq == 2) ? 23 - jj : 8 + jj;
  const int bh = ((id & 7) << 2) | ((id >> 3) & 3);  // xcd-major for L2 locality

  const size_t base = (size_t)bh * (SEQ * DHEAD);  // also = bh*64*SEQ for V^T
  const bool causal = (amask[0] != 0);
  const int nt = causal ? (qi + 1) : (SEQ / 64);
  const int b = bh >> 4, h = bh & 15;
  const int qrow = qi * 64 + (w << 4) + l16;  // this lane's q

  // Q fragments (pre-scaled by 0.125*log2e): B-operand, lane col = q.
  bf16x8 qf[2];
  {
    const u16* qp = Qb + base + (size_t)qrow * DHEAD + (lg << 3);
    qf[0] = *(const bf16x8*)qp;
    qf[1] = *(const bf16x8*)(qp + 32);
  }

  float mrow = -1e30f, lrowp = 0.f;  // per-lane partial row sum
  f32x4 oacc[4] = {};

  const int key = (l16 & 7) << 2;
  char* prow = (char*)(&Ps[w][0]) + l16 * 128;  // 32 words per q-row

  // prologue: stage kv-tile 0
  stage_k64(Kb, base, 0, Ks[0], w, lane);
  stage_v64(VTg, base, 0, Vt[0], w, lane);
  __syncthreads();

  int cur = 0;
  for (int t = 0; t < nt; ++t) {
    const u16* Kcur = Ks[cur];
    const u16* Vcur = Vt[cur];
    const bool pre = (t + 1 < nt);
    if (pre) stage_k64(Kb, base, t + 1, Ks[cur ^ 1], w, lane);

    // S^T = K Q^T : sv[nf], kv = nf*16 + lg*4 + i, col q = l16
    f32x4 sv[4];
    __builtin_amdgcn_s_setprio(1);
#pragma unroll
    for (int nf = 0; nf < 4; ++nf) {
      const int r2 = (nf << 3) | (l16 >> 1);       // row = kv>>1
      const int sz = swz4(r2);
      const int s0 = ((l16 & 1) << 3) | lg;
      bf16x8 kf0 = *(const bf16x8*)((const char*)Kcur + r2 * 256 + ((s0 ^ sz) << 4));
      bf16x8 kf1 = *(const bf16x8*)((const char*)Kcur + r2 * 256 + (((s0 | 4) ^ sz) << 4));
      f32x4 s = {};
      s = mfma16(kf0, qf[0], s);
      s = mfma16(kf1, qf[1], s);
      sv[nf] = s;
    }
    __builtin_amdgcn_s_setprio(0);

    if (causal && (t == nt - 1)) {  // diagonal tile: mask kv > q
#pragma unroll
      for (int nf = 0; nf < 4; ++nf)
#pragma unroll
        for (int i = 0; i < 4; ++i) {
          const int kv = t * 64 + (nf << 4) + (lg << 2) + i;
          if (kv > qrow) sv[nf][i] = -1e30f;
        }
    }

    // tile max: in-lane tree + 2 shuffles across lg
    float tmaxg;
    {
      f32x4 mt;
#pragma unroll
      for (int i = 0; i < 4; ++i)
        mt[i] = fmaxf(fmaxf(sv[0][i], sv[1][i]), fmaxf(sv[2][i], sv[3][i]));
      tmaxg = fmaxf(fmaxf(mt[0], mt[1]), fmaxf(mt[2], mt[3]));
      tmaxg = fmaxf(tmaxg, __shfl_xor(tmaxg, 16));
      tmaxg = fmaxf(tmaxg, __shfl_xor(tmaxg, 32));
    }

    // defer-max (T13, log2 domain)
    if (__any(tmaxg > mrow + 8.0f)) {
      const float mnew = fmaxf(mrow, tmaxg);
      const float corr = __builtin_amdgcn_exp2f(mrow - mnew);
      lrowp *= corr;
#pragma unroll
      for (int df = 0; df < 4; ++df)
#pragma unroll
        for (int i = 0; i < 4; ++i) oacc[df][i] *= corr;
      mrow = mnew;
    }

    // P = exp2(S - m): per-lane partials, pack, store to per-wave LDS
#pragma unroll
    for (int nf = 0; nf < 4; ++nf) {
      const float p0 = __builtin_amdgcn_exp2f(sv[nf][0] - mrow);
      const float p1 = __builtin_amdgcn_exp2f(sv[nf][1] - mrow);
      const float p2 = __builtin_amdgcn_exp2f(sv[nf][2] - mrow);
      const float p3 = __builtin_amdgcn_exp2f(sv[nf][3] - mrow);
      lrowp += (p0 + p1) + (p2 + p3);
      uint2 pkv;
      pkv.x = pk2(p0, p1);
      pkv.y = pk2(p2, p3);
      const int word = ((nf << 3) | (lg << 1)) ^ key;
      *(uint2*)(prow + word * 4) = pkv;
    }

    // V prefetch mid-iteration (lands during PV + next QK)
    if (pre) stage_v64(VTg, base, t + 1, Vt[cur ^ 1], w, lane);

    // reload P as B-operand frags: pa[s], kv = 32s + lg*8 + e
    bf16x8 pa[2];
    pa[0] = *(const bf16x8*)(prow + ((((lg << 2)) ^ key) << 2));
    pa[1] = *(const bf16x8*)(prow + (((16 | (lg << 2)) ^ key) << 2));

    // O^T += V^T P^T  (A-frag: d-row = df*16+l16, kv-chunk = s*4+lg)
    __builtin_amdgcn_s_setprio(1);
#pragma unroll
    for (int df = 0; df < 4; ++df) {
      const int r2 = (df << 3) | (l16 >> 1);
      const int sz = swz4(r2);
      const int pb = (l16 & 1) << 3;
#pragma unroll
      for (int s = 0; s < 2; ++s) {
        bf16x8 vf = *(const bf16x8*)((const char*)Vcur + r2 * 256 +
                                     (((pb | (s << 2) | lg) ^ sz) << 4));
        oacc[df] = mfma16(vf, pa[s], oacc[df]);
      }
    }
    __builtin_amdgcn_s_setprio(0);

    if (pre) __syncthreads();
    cur ^= 1;
  }

  // epilogue: reduce per-lane partial row sums, O /= l, write bf16
  {
    float lrow = lrowp + __shfl_xor(lrowp, 16);
    lrow += __shfl_xor(lrow, 32);
    const float inv = 1.0f / lrow;
    u16* orow = Ob + (size_t)(b * SEQ + qrow) * DEMB + h * DHEAD;
#pragma unroll
    for (int df = 0; df < 4; ++df) {
      ushort4 o;
      o.x = f2b(oacc[df][0] * inv);
      o.y = f2b(oacc[df][1] * inv);
      o.z = f2b(oacc[df][2] * inv);
      o.w = f2b(oacc[df][3] * inv);
      *(ushort4*)(orow + (df << 4) + (lg << 2)) = o;
    }
  }
}

extern "C" void kernel_launch(void* const* d_in, const int* in_sizes, int n_in,
                              void* d_out, int out_size, void* d_ws, size_t ws_size,
                              hipStream_t stream) {
  const float* x = (const float*)d_in[0];
  const float* w_in = (const float*)d_in[1];
  const float* b_in = (const float*)d_in[2];
  const float* w_out = (const float*)d_in[3];
  const float* b_out = (const float*)d_in[4];
  const int* amask = (const int*)d_in[5];
  float* out = (float*)d_out;

  u16* xb = (u16*)d_ws;
  u16* wib = xb + (size_t)MROWS * DEMB;
  u16* wob = wib + (size_t)3 * DEMB * DEMB;
  u16* Qb = wob + (size_t)DEMB * DEMB;
  u16* Kb = Qb + (size_t)MROWS * DEMB;
  u16* Vtg = Kb + (size_t)MROWS * DEMB;  // transposed V: [bh][d][s]
  u16* Ab = xb;  // attn output reuses x-bf16 region

  cvt3_f32_bf16<<<2048, 256, 0, stream>>>(x, MROWS * DEMB, w_in, 3 * DEMB * DEMB,
                                          w_out, DEMB * DEMB, xb, wib, wob);

  gemm_nt<0><<<dim3(24, 32), 256, 0, stream>>>(xb, wib, b_in, DEMB, 3 * DEMB,
                                               Qb, Kb, Vtg, nullptr);
  attn_fwd<<<1024, 256, 0, stream>>>(Qb, Kb, Vtg, Ab, amask);
  gemm_nt<1><<<dim3(8, 32), 256, 0, stream>>>(Ab, wob, b_out, DEMB, DEMB,
                                              nullptr, nullptr, nullptr, out);
}

// Round 16
// 102.688 us; speedup vs baseline: 1.0484x; 1.0484x over previous
//
#include <hip/hip_runtime.h>
#include <stdint.h>

#define DEMB 1024
#define NHEAD 16
#define DHEAD 64
#define SEQ 2048
#define MROWS 4096  // B*S

typedef __bf16 bf16x8 __attribute__((ext_vector_type(8)));
typedef float f32x4 __attribute__((ext_vector_type(4)));
typedef unsigned short u16;

#define LOG2E 1.44269504088896340736f

__device__ __forceinline__ u16 f2b(float f) {
  return __builtin_bit_cast(u16, (__bf16)f);  // RNE, compiler can pack pairs
}
__device__ __forceinline__ uint32_t pk2(float a, float b) {
  return (uint32_t)f2b(a) | ((uint32_t)f2b(b) << 16);
}

__device__ __forceinline__ f32x4 mfma16(bf16x8 a, bf16x8 b, f32x4 c) {
  return __builtin_amdgcn_mfma_f32_16x16x32_bf16(a, b, c, 0, 0, 0);
}

__device__ __forceinline__ void gload_lds16(const void* g, void* l) {
  __builtin_amdgcn_global_load_lds(
      (__attribute__((address_space(1))) unsigned int*)(g),
      (__attribute__((address_space(3))) unsigned int*)(l), 16, 0, 0);
}

// fused fp32->bf16 convert of three regions (sizes all multiples of 4)
__global__ void cvt3_f32_bf16(const float* __restrict__ a, int na,
                              const float* __restrict__ b, int nb,
                              const float* __restrict__ c, int nc,
                              u16* __restrict__ da, u16* __restrict__ db,
                              u16* __restrict__ dc) {
  const int total = (na + nb + nc) >> 2;
  const int stride = gridDim.x * blockDim.x;
  for (int t = blockIdx.x * blockDim.x + threadIdx.x; t < total; t += stride) {
    int i = t << 2;
    const float* s;
    u16* d;
    if (i < na) {
      s = a + i; d = da + i;
    } else if (i < na + nb) {
      s = b + (i - na); d = db + (i - na);
    } else {
      s = c + (i - na - nb); d = dc + (i - na - nb);
    }
    float4 f = *(const float4*)s;
    ushort4 o;
    o.x = f2b(f.x); o.y = f2b(f.y); o.z = f2b(f.z); o.w = f2b(f.w);
    *(ushort4*)d = o;
  }
}

// NT GEMM (single-buffered, occupancy-first: 32 KB LDS + launch_bounds(256,4)
// -> 4 blocks/CU; cross-block wave overlap hides staging latency. Explicit
// dbuf regressed twice (rounds 10/13) by halving blocks/CU).
// EPI==0: scatter Q,K to [B,H,S,Dh] bf16 (Q pre-scaled by 0.125*log2e);
//         V written TRANSPOSED: Vt[bh][d][s].
// EPI==1: write fp32 C[m*N+n].
template <int EPI>
__global__ __launch_bounds__(256, 4) void gemm_nt(
    const u16* __restrict__ A, const u16* __restrict__ Bw,
    const float* __restrict__ bias, int K, int N,
    u16* __restrict__ q_out, u16* __restrict__ k_out, u16* __restrict__ v_out,
    float* __restrict__ f_out) {
  __shared__ __align__(16) u16 As[128 * 64];
  __shared__ __align__(16) u16 Bs[128 * 64];
  const int tid = threadIdx.x;
  const int w = tid >> 6;
  const int lane = tid & 63;
  const int wm = w >> 1, wn = w & 1;
  const int m0 = blockIdx.y * 128, n0 = blockIdx.x * 128;
  const int l16 = lane & 15, lg = lane >> 4;
  const int st_row = lane >> 3, st_slot = lane & 7;

  f32x4 acc[4][4] = {};

  for (int k0 = 0; k0 < K; k0 += 64) {
#pragma unroll
    for (int i = 0; i < 4; ++i) {
      const int chunk = (w << 2) | i;
      const int row = (chunk << 3) | st_row;
      const int scol = (st_slot ^ (row & 7)) << 3;
      gload_lds16(A + (size_t)(m0 + row) * K + k0 + scol, (char*)As + (chunk << 10));
      gload_lds16(Bw + (size_t)(n0 + row) * K + k0 + scol, (char*)Bs + (chunk << 10));
    }
    __syncthreads();
#pragma unroll
    for (int ks = 0; ks < 2; ++ks) {
      bf16x8 af[4], bfr[4];
#pragma unroll
      for (int mi = 0; mi < 4; ++mi) {
        const int row = wm * 64 + mi * 16 + l16;
        const int cb = ((ks << 6) | (lg << 4)) ^ ((row & 7) << 4);
        af[mi] = *(const bf16x8*)((const char*)As + row * 128 + cb);
      }
#pragma unroll
      for (int ni = 0; ni < 4; ++ni) {
        const int row = wn * 64 + ni * 16 + l16;
        const int cb = ((ks << 6) | (lg << 4)) ^ ((row & 7) << 4);
        bfr[ni] = *(const bf16x8*)((const char*)Bs + row * 128 + cb);
      }
#pragma unroll
      for (int mi = 0; mi < 4; ++mi)
#pragma unroll
        for (int ni = 0; ni < 4; ++ni)
          acc[mi][ni] = mfma16(af[mi], bfr[ni], acc[mi][ni]);
    }
    __syncthreads();
  }

#pragma unroll
  for (int ni = 0; ni < 4; ++ni) {
    const int n = n0 + wn * 64 + ni * 16 + l16;
    const float bv = bias[n];
    if (EPI == 0) {
      const int part = n >> 10;
      const int hh = (n >> 6) & 15;
      const int dh = n & 63;
      if (part == 2) {
        // V^T: [bh][d][s], 4 consecutive s per ushort4
#pragma unroll
        for (int mi = 0; mi < 4; ++mi) {
          const int mbase = m0 + wm * 64 + mi * 16 + (lg << 2);
          const int bq = mbase >> 11, s0 = mbase & 2047;
          ushort4 o;
          o.x = f2b(acc[mi][ni][0] + bv);
          o.y = f2b(acc[mi][ni][1] + bv);
          o.z = f2b(acc[mi][ni][2] + bv);
          o.w = f2b(acc[mi][ni][3] + bv);
          *(ushort4*)(v_out + ((size_t)(((bq << 4) | hh) * 64 + dh)) * SEQ + s0) = o;
        }
      } else {
        const float scl = (part == 0) ? (0.125f * LOG2E) : 1.0f;
        u16* dst = (part == 0) ? q_out : k_out;
#pragma unroll
        for (int mi = 0; mi < 4; ++mi) {
#pragma unroll
          for (int i = 0; i < 4; ++i) {
            const int m = m0 + wm * 64 + mi * 16 + (lg << 2) + i;
            const int bq = m >> 11, s = m & 2047;
            dst[((size_t)((bq << 4) | hh) * SEQ + s) * DHEAD + dh] = f2b((acc[mi][ni][i] + bv) * scl);
          }
        }
      }
    } else {
#pragma unroll
      for (int mi = 0; mi < 4; ++mi)
#pragma unroll
        for (int i = 0; i < 4; ++i) {
          const int m = m0 + wm * 64 + mi * 16 + (lg << 2) + i;
          f_out[(size_t)m * N + n] = acc[mi][ni][i] + bv;
        }
    }
  }
}

// ---- attention (4 waves, QBLK=64 paired, KVBLK=128, split prefetch) ----
__device__ __forceinline__ int swz4(int r) { return (r ^ (r >> 3)) & 15; }

// K tile: 128 kv x 64 d packed as LDS [64 rows][256B]; row r2 holds kv {2r2, 2r2+1}.
__device__ __forceinline__ void stage_k(const u16* __restrict__ Kb, size_t base,
                                        int jt, u16* Ks, int w, int lane) {
#pragma unroll
  for (int i = 0; i < 4; ++i) {
    const int g = (w << 2) | i;               // 0..15: 1KB chunk id
    const int row = (g << 2) | (lane >> 4);   // LDS row 0..63
    const int shat = (lane & 15) ^ swz4(row); // unswizzled slot
    const int kv = (row << 1) | (shat >> 3);
    const int del = (shat & 7) << 3;
    gload_lds16(Kb + base + (size_t)(jt * 128 + kv) * DHEAD + del,
                (char*)Ks + (g << 10));
  }
}

// V tile from pre-transposed global Vt[bh][d][s]: LDS [64 d-rows][256B=128 kv].
__device__ __forceinline__ void stage_v(const u16* __restrict__ VTg, size_t base,
                                        int jt, u16* Vs, int w, int lane) {
#pragma unroll
  for (int i = 0; i < 4; ++i) {
    const int g = (w << 2) | i;
    const int row = (g << 2) | (lane >> 4);   // d row 0..63
    const int shat = (lane & 15) ^ swz4(row);
    gload_lds16(VTg + base + (size_t)row * SEQ + jt * 128 + (shat << 3),
                (char*)Vs + (g << 10));
  }
}

// Swapped-operand flash attention. QBLK=64 (4 waves x 16 q), KVBLK=128, dbuf.
// Pair (31-p, p): uniform 17 causal kv-iterations per block; 512 blocks.
__global__ __launch_bounds__(256, 2) void attn_fwd(
    const u16* __restrict__ Qb, const u16* __restrict__ Kb,
    const u16* __restrict__ VTg, u16* __restrict__ Ob,
    const int* __restrict__ amask) {
  __shared__ __align__(16) u16 Ks[2][64 * 128];
  __shared__ __align__(16) u16 Vt[2][64 * 128];
  __shared__ __align__(16) uint32_t Ps[4][1024];  // per-wave 16q x 128kv bf16
  const int tid = threadIdx.x;
  const int w = tid >> 6, lane = tid & 63;
  const int l16 = lane & 15, lg = lane >> 4;

  const int id = blockIdx.x;
  const int xcd = id & 7;
  const int r = id >> 3;
  const int bh = (xcd << 2) | (r & 3);
  const int p = r >> 2;  // 0..15
  const int qiA = 31 - p, qiB = p;

  const size_t base = (size_t)bh * (SEQ * DHEAD);  // also = bh*64*SEQ for V^T
  const bool causal = (amask[0] != 0);
  const int ntA = causal ? ((qiA >> 1) + 1) : (SEQ / 128);
  const int ntB = causal ? ((qiB >> 1) + 1) : (SEQ / 128);
  const int nt = ntA + ntB;
  const int b = bh >> 4, h = bh & 15;

  int qseg0 = qiA * 64;

  // Q fragments (pre-scaled by 0.125*log2e): B-operand, lane col = q = l16.
  bf16x8 qf[2];
  {
    const u16* qp = Qb + base + (size_t)(qseg0 + (w << 4) + l16) * DHEAD + (lg << 3);
    qf[0] = *(const bf16x8*)qp;
    qf[1] = *(const bf16x8*)(qp + 32);
  }

  float mrow = -1e30f, lrowp = 0.f;  // lrowp: per-lane partial row sum
  f32x4 oacc[4] = {};

  const int key = (l16 & 7) << 2;
  char* prow = (char*)(&Ps[w][0]) + l16 * 256;

  // prologue: stage kv-tile 0
  stage_k(Kb, base, 0, Ks[0], w, lane);
  stage_v(VTg, base, 0, Vt[0], w, lane);
  __syncthreads();

  int cur = 0;
  for (int t = 0; t < nt; ++t) {
    const int j = (t >= ntA) ? (t - ntA) : t;
    const u16* Kcur = Ks[cur];
    const u16* Vcur = Vt[cur];
    const bool pre = (t + 1 < nt);
    const int jn = (t + 1 >= ntA) ? (t + 1 - ntA) : (t + 1);
    if (pre) stage_k(Kb, base, jn, Ks[cur ^ 1], w, lane);

    // S^T = K Q^T : sv[nf], kv = nf*16 + lg*4 + i, col q = l16
    f32x4 sv[8];
    __builtin_amdgcn_s_setprio(1);
#pragma unroll
    for (int nf = 0; nf < 8; ++nf) {
      const int row2 = (nf << 3) | (l16 >> 1);     // LDS row (kv>>1)
      const int sz = swz4(row2);
      const int s0 = ((l16 & 1) << 3) | lg;
      bf16x8 kf0 = *(const bf16x8*)((const char*)Kcur + row2 * 256 + ((s0 ^ sz) << 4));
      bf16x8 kf1 = *(const bf16x8*)((const char*)Kcur + row2 * 256 + (((s0 | 4) ^ sz) << 4));
      f32x4 s = {};
      s = mfma16(kf0, qf[0], s);
      s = mfma16(kf1, qf[1], s);
      sv[nf] = s;
    }
    __builtin_amdgcn_s_setprio(0);

    const bool segEnd = (t == ntA - 1) || (t == nt - 1);
    if (causal && segEnd) {  // diagonal tile: mask kv > q
      const int q = qseg0 + (w << 4) + l16;
#pragma unroll
      for (int nf = 0; nf < 8; ++nf)
#pragma unroll
        for (int i = 0; i < 4; ++i) {
          const int kv = j * 128 + (nf << 4) + (lg << 2) + i;
          if (kv > q) sv[nf][i] = -1e30f;
        }
    }

    // tile max: pairwise tree in-lane + 2 shuffles across lg
    float tmaxg;
    {
      f32x4 mt;
#pragma unroll
      for (int i = 0; i < 4; ++i) {
        const float a01 = fmaxf(sv[0][i], sv[1][i]);
        const float a23 = fmaxf(sv[2][i], sv[3][i]);
        const float a45 = fmaxf(sv[4][i], sv[5][i]);
        const float a67 = fmaxf(sv[6][i], sv[7][i]);
        mt[i] = fmaxf(fmaxf(a01, a23), fmaxf(a45, a67));
      }
      tmaxg = fmaxf(fmaxf(mt[0], mt[1]), fmaxf(mt[2], mt[3]));
      tmaxg = fmaxf(tmaxg, __shfl_xor(tmaxg, 16));
      tmaxg = fmaxf(tmaxg, __shfl_xor(tmaxg, 32));
    }

    // defer-max (T13, log2 domain): rescale only when the max grew > 8
    if (__any(tmaxg > mrow + 8.0f)) {
      const float mnew = fmaxf(mrow, tmaxg);
      const float corr = __builtin_amdgcn_exp2f(mrow - mnew);
      lrowp *= corr;
#pragma unroll
      for (int df = 0; df < 4; ++df)
#pragma unroll
        for (int i = 0; i < 4; ++i) oacc[df][i] *= corr;
      mrow = mnew;
    }

    // P = exp2(S - m): accumulate per-lane partials, pack, store to LDS
#pragma unroll
    for (int nf = 0; nf < 8; ++nf) {
      const float p0 = __builtin_amdgcn_exp2f(sv[nf][0] - mrow);
      const float p1 = __builtin_amdgcn_exp2f(sv[nf][1] - mrow);
      const float p2 = __builtin_amdgcn_exp2f(sv[nf][2] - mrow);
      const float p3 = __builtin_amdgcn_exp2f(sv[nf][3] - mrow);
      lrowp += (p0 + p1) + (p2 + p3);
      uint2 pkv;
      pkv.x = pk2(p0, p1);
      pkv.y = pk2(p2, p3);
      const int word = ((nf << 3) | (lg << 1)) ^ key;
      *(uint2*)(prow + word * 4) = pkv;
    }

    // V prefetch issued mid-iteration: lands during PV + next iteration's QK
    if (pre) stage_v(VTg, base, jn, Vt[cur ^ 1], w, lane);

    // reload P as B-operand frags: pa[s], kv = 32s + lg*8 + e
    bf16x8 pa[4];
#pragma unroll
    for (int s = 0; s < 4; ++s)
      pa[s] = *(const bf16x8*)(prow + ((((s << 4) | (lg << 2)) ^ key) << 2));

    // O^T += V^T P^T
    __builtin_amdgcn_s_setprio(1);
#pragma unroll
    for (int df = 0; df < 4; ++df) {
      const int row = (df << 4) + l16;
      const int sz = swz4(row) << 4;
#pragma unroll
      for (int s = 0; s < 4; ++s) {
        bf16x8 vf = *(const bf16x8*)((const char*)Vcur + row * 256 + (((s << 6) | (lg << 4)) ^ sz));
        oacc[df] = mfma16(vf, pa[s], oacc[df]);
      }
    }
    __builtin_amdgcn_s_setprio(0);

    if (segEnd) {
      // full row sum: reduce per-lane partials across the 4 lane-groups
      float lrow = lrowp + __shfl_xor(lrowp, 16);
      lrow += __shfl_xor(lrow, 32);
      const float inv = 1.0f / lrow;
      const int s = qseg0 + (w << 4) + l16;
      u16* orow = Ob + (size_t)(b * SEQ + s) * DEMB + h * DHEAD;
#pragma unroll
      for (int df = 0; df < 4; ++df) {
        ushort4 o;
        o.x = f2b(oacc[df][0] * inv);
        o.y = f2b(oacc[df][1] * inv);
        o.z = f2b(oacc[df][2] * inv);
        o.w = f2b(oacc[df][3] * inv);
        *(ushort4*)(orow + (df << 4) + (lg << 2)) = o;
      }
      if (t != nt - 1) {  // switch to segment B
        qseg0 = qiB * 64;
        mrow = -1e30f;
        lrowp = 0.f;
#pragma unroll
        for (int df = 0; df < 4; ++df)
#pragma unroll
          for (int i = 0; i < 4; ++i) oacc[df][i] = 0.f;
        const u16* qp = Qb + base + (size_t)(qseg0 + (w << 4) + l16) * DHEAD + (lg << 3);
        qf[0] = *(const bf16x8*)qp;
        qf[1] = *(const bf16x8*)(qp + 32);
      }
    }

    if (pre) __syncthreads();
    cur ^= 1;
  }
}

extern "C" void kernel_launch(void* const* d_in, const int* in_sizes, int n_in,
                              void* d_out, int out_size, void* d_ws, size_t ws_size,
                              hipStream_t stream) {
  const float* x = (const float*)d_in[0];
  const float* w_in = (const float*)d_in[1];
  const float* b_in = (const float*)d_in[2];
  const float* w_out = (const float*)d_in[3];
  const float* b_out = (const float*)d_in[4];
  const int* amask = (const int*)d_in[5];
  float* out = (float*)d_out;

  u16* xb = (u16*)d_ws;
  u16* wib = xb + (size_t)MROWS * DEMB;
  u16* wob = wib + (size_t)3 * DEMB * DEMB;
  u16* Qb = wob + (size_t)DEMB * DEMB;
  u16* Kb = Qb + (size_t)MROWS * DEMB;
  u16* Vtg = Kb + (size_t)MROWS * DEMB;  // transposed V: [bh][d][s]
  u16* Ab = xb;  // attn output reuses x-bf16 region

  cvt3_f32_bf16<<<2048, 256, 0, stream>>>(x, MROWS * DEMB, w_in, 3 * DEMB * DEMB,
                                          w_out, DEMB * DEMB, xb, wib, wob);

  gemm_nt<0><<<dim3(24, 32), 256, 0, stream>>>(xb, wib, b_in, DEMB, 3 * DEMB,
                                               Qb, Kb, Vtg, nullptr);
  attn_fwd<<<512, 256, 0, stream>>>(Qb, Kb, Vtg, Ab, amask);
  gemm_nt<1><<<dim3(8, 32), 256, 0, stream>>>(Ab, wob, b_out, DEMB, DEMB,
                                              nullptr, nullptr, nullptr, out);
}